// Round 19
// baseline (27.439 us; speedup 1.0000x reference)
//
#include <hip/hip_runtime.h>
#include <hip/hip_bf16.h>
#include <math.h>

#define NSENT 256
#define SLEN  512
#define VROWS 50000
#define EDIM  300
#define NROW  12
#define SSTR  16              // score-row stride (floats): 64B rows
#define NSTEP 10              // K-steps of 16x16x32 MFMA
#define RPB   32              // vocab rows per block
#define TILEB (RPB * EDIM * 4)        // 38400 B staged per block
#define NCHUNK 38                      // ceil(38400/1024) 1KB wave-chunks
#define NBLKA ((VROWS + RPB - 1) / RPB)   // 1563

typedef __attribute__((ext_vector_type(8))) short bf16x8;
typedef __attribute__((ext_vector_type(4))) float f32x4;

static __device__ __forceinline__ short f2bf(float f) {
    __hip_bfloat16 h = __float2bfloat16(f);   // RNE
    short s;
    __builtin_memcpy(&s, &h, sizeof(s));
    return s;
}

// ---------------------------------------------------------------------------
// Kernel A, round-19: vocab scores via bf16 MFMA with ASYNC DMA staging.
// global_load_lds (16B/lane, 1KB/wave-chunk) stages 32 emb rows to LDS with
// zero VGPR round-trip; 38 chunks stay in flight until the barrier drains
// vmcnt. Wave (t,h) computes tile t (16 rows) x K-half h (5 MFMA steps),
// A-frags read from LDS (fp32->bf16 cvt in reg); K-half partials summed via
// LDS. 52KB LDS -> 3 blocks/CU.
// ---------------------------------------------------------------------------
__global__ __launch_bounds__(256, 3)
void vocab_scores_mfma(const float* __restrict__ emb,
                       const float* __restrict__ k3,
                       const float* __restrict__ k4,
                       const float* __restrict__ k5,
                       float* __restrict__ s)
{
    __shared__ float4 ebuf4[NCHUNK * 64];      // 38912 B (chunk 37 spills past 38400)
    __shared__ bf16x8 bfrag_lds[NSTEP * 64];   // 10240 B
    __shared__ f32x4  part[4][64];             //  4096 B

    const int tid  = threadIdx.x;
    const int lane = tid & 63;
    const int wave = tid >> 6;      // 0..3
    const int rc   = lane & 15;     // A-row-in-tile / D-col (conv row)
    const int kg   = lane >> 4;     // k-group 0..3

    char* ebuf = reinterpret_cast<char*>(ebuf4);
    const size_t EMB_END = (size_t)VROWS * EDIM * 4;   // 60,000,000 B
    const size_t tbase   = (size_t)blockIdx.x * TILEB;

    // ---- async stage: 38 x 1KB chunks, per-lane global, uniform LDS dest --
    for (int c = wave; c < NCHUNK; c += 4) {
        size_t gb = tbase + (size_t)c * 1024 + (size_t)lane * 16;
        if (gb > EMB_END - 16) gb = EMB_END - 16;          // clamp tail
        const void* gp = (const char*)emb + gb;
        void* lp = ebuf + c * 1024;                        // wave-uniform
        __builtin_amdgcn_global_load_lds(
            (const __attribute__((address_space(1))) void*)gp,
            (__attribute__((address_space(3))) void*)lp,
            16, 0, 0);
    }

    // ---- B-frag build overlaps the DMA drain ------------------------------
    for (int e = tid; e < NSTEP * 64; e += 256) {
        const int st  = e >> 6;
        const int le  = e & 63;
        const int rce = le & 15;
        const int kge = le >> 4;
        const float* krow = nullptr;
        if      (rce < 3)  krow = k3 + rce * EDIM;
        else if (rce < 7)  krow = k4 + (rce - 3) * EDIM;
        else if (rce < 12) krow = k5 + (rce - 7) * EDIM;
        const int k0 = st * 32 + kge * 8;
        float4 b0 = make_float4(0.f,0.f,0.f,0.f);
        float4 b1 = make_float4(0.f,0.f,0.f,0.f);
        if (krow) {
            if (k0 + 4 <= EDIM) b0 = *reinterpret_cast<const float4*>(krow + k0);
            if (k0 + 8 <= EDIM) b1 = *reinterpret_cast<const float4*>(krow + k0 + 4);
        }
        bf16x8 f;
        f[0]=f2bf(b0.x); f[1]=f2bf(b0.y); f[2]=f2bf(b0.z); f[3]=f2bf(b0.w);
        f[4]=f2bf(b1.x); f[5]=f2bf(b1.y); f[6]=f2bf(b1.z); f[7]=f2bf(b1.w);
        bfrag_lds[e] = f;
    }
    __syncthreads();   // drains vmcnt(0) (DMA) + lgkmcnt, then barrier

    // ---- compute: wave = (tile t, K-half h); 5 MFMA steps -----------------
    const int t = wave >> 1;        // 0..1
    const int h = wave & 1;         // 0..1
    const int lrow = t * 16 + rc;   // row within the 32-row tile

    f32x4 acc = {0.f, 0.f, 0.f, 0.f};
    #pragma unroll
    for (int st = 0; st < 5; ++st) {
        const int koff = ((h * 5 + st) * 32 + kg * 8) * 4;   // byte offset in row
        const char* p = ebuf + lrow * 1200 + koff;
        const float4 f0 = *reinterpret_cast<const float4*>(p);
        const float4 f1 = *reinterpret_cast<const float4*>(p + 16);
        bf16x8 af;
        af[0]=f2bf(f0.x); af[1]=f2bf(f0.y); af[2]=f2bf(f0.z); af[3]=f2bf(f0.w);
        af[4]=f2bf(f1.x); af[5]=f2bf(f1.y); af[6]=f2bf(f1.z); af[7]=f2bf(f1.w);
        const bf16x8 bf = bfrag_lds[(h * 5 + st) * 64 + lane];
        acc = __builtin_amdgcn_mfma_f32_16x16x32_bf16(af, bf, acc, 0, 0, 0);
    }

    part[wave][lane] = acc;
    __syncthreads();

    // ---- reduce K-halves and store (waves 0,1 own tile 0,1) ---------------
    if (wave < 2) {
        const f32x4 p0 = part[wave * 2 + 0][lane];
        const f32x4 p1 = part[wave * 2 + 1][lane];
        if (rc < NROW) {
            #pragma unroll
            for (int j = 0; j < 4; ++j) {
                const int v = blockIdx.x * RPB + wave * 16 + kg * 4 + j;
                if (v < VROWS) s[(size_t)v * SSTR + rc] = p0[j] + p1[j];
            }
        }
    }
}

// ---------------------------------------------------------------------------
// Kernel B (byte-identical to round 14): 512 thr / sentence, 1 token/thread,
// single-line 64B gathers -> LDS planes -> windows + tanh + max + fc +
// log_softmax.
// ---------------------------------------------------------------------------
__global__ __launch_bounds__(512, 1)
void textcnn_finish(const int*   __restrict__ sent,
                    const float* __restrict__ s,
                    const float* __restrict__ b3,
                    const float* __restrict__ b4,
                    const float* __restrict__ b5,
                    const float* __restrict__ fcw,
                    const float* __restrict__ fcb,
                    float* __restrict__ out)
{
    __shared__ float s_lds[NROW * SLEN];
    __shared__ float red[8][3];

    const int b = blockIdx.x;
    const int t = threadIdx.x;

    const int widx = sent[b * SLEN + t];
    const float4* row = reinterpret_cast<const float4*>(s + (size_t)widx * SSTR);
    const float4 sa = row[0];
    const float4 sb = row[1];
    const float4 sc = row[2];

    const float bb3 = b3[0], bb4 = b4[0], bb5 = b5[0];

    s_lds[ 0*SLEN + t] = sa.x;  s_lds[ 1*SLEN + t] = sa.y;
    s_lds[ 2*SLEN + t] = sa.z;  s_lds[ 3*SLEN + t] = sa.w;
    s_lds[ 4*SLEN + t] = sb.x;  s_lds[ 5*SLEN + t] = sb.y;
    s_lds[ 6*SLEN + t] = sb.z;  s_lds[ 7*SLEN + t] = sb.w;
    s_lds[ 8*SLEN + t] = sc.x;  s_lds[ 9*SLEN + t] = sc.y;
    s_lds[10*SLEN + t] = sc.z;  s_lds[11*SLEN + t] = sc.w;
    __syncthreads();

    float m3 = -1e30f, m4 = -1e30f, m5 = -1e30f;
    if (t < SLEN - 2)
        m3 = tanhf(s_lds[0*SLEN + t] + s_lds[1*SLEN + t+1] +
                   s_lds[2*SLEN + t+2] + bb3);
    if (t < SLEN - 3)
        m4 = tanhf(s_lds[3*SLEN + t] + s_lds[4*SLEN + t+1] +
                   s_lds[5*SLEN + t+2] + s_lds[6*SLEN + t+3] + bb4);
    if (t < SLEN - 4)
        m5 = tanhf(s_lds[7*SLEN + t] + s_lds[8*SLEN + t+1] +
                   s_lds[9*SLEN + t+2] + s_lds[10*SLEN + t+3] +
                   s_lds[11*SLEN + t+4] + bb5);

    #pragma unroll
    for (int off = 32; off; off >>= 1) {
        m3 = fmaxf(m3, __shfl_xor(m3, off));
        m4 = fmaxf(m4, __shfl_xor(m4, off));
        m5 = fmaxf(m5, __shfl_xor(m5, off));
    }
    if ((t & 63) == 0) {
        const int w = t >> 6;
        red[w][0] = m3; red[w][1] = m4; red[w][2] = m5;
    }
    __syncthreads();

    if (t == 0) {
        float f3 = red[0][0], f4 = red[0][1], f5 = red[0][2];
        #pragma unroll
        for (int w = 1; w < 8; ++w) {
            f3 = fmaxf(f3, red[w][0]);
            f4 = fmaxf(f4, red[w][1]);
            f5 = fmaxf(f5, red[w][2]);
        }
        float lg[10];
        float mx = -1e30f;
        #pragma unroll
        for (int c = 0; c < 10; ++c) {
            lg[c] = fcb[c] + f3 * fcw[c*3+0] + f4 * fcw[c*3+1] + f5 * fcw[c*3+2];
            mx = fmaxf(mx, lg[c]);
        }
        float ssum = 0.f;
        #pragma unroll
        for (int c = 0; c < 10; ++c) ssum += expf(lg[c] - mx);
        const float lse = logf(ssum);
        #pragma unroll
        for (int c = 0; c < 10; ++c) out[b * 10 + c] = lg[c] - mx - lse;
    }
}

extern "C" void kernel_launch(void* const* d_in, const int* in_sizes, int n_in,
                              void* d_out, int out_size, void* d_ws, size_t ws_size,
                              hipStream_t stream) {
    const int*   sent = (const int*)  d_in[0];
    const float* emb  = (const float*)d_in[1];
    const float* k3   = (const float*)d_in[2];
    const float* b3   = (const float*)d_in[3];
    const float* k4   = (const float*)d_in[4];
    const float* b4   = (const float*)d_in[5];
    const float* k5   = (const float*)d_in[6];
    const float* b5   = (const float*)d_in[7];
    const float* fcw  = (const float*)d_in[8];
    const float* fcb  = (const float*)d_in[9];
    float* out = (float*)d_out;
    float* s   = (float*)d_ws;        // VROWS * 16 * 4 B = 3.2 MB

    vocab_scores_mfma<<<NBLKA, 256, 0, stream>>>(emb, k3, k4, k5, s);
    textcnn_finish<<<NSENT, 512, 0, stream>>>(sent, s, b3, b4, b5, fcw, fcb, out);
}